// Round 1
// baseline (2303.457 us; speedup 1.0000x reference)
//
#include <hip/hip_runtime.h>

__device__ __forceinline__ float silu_f(float x) {
  return x / (1.0f + __expf(-x));
}

// C[M x 256] = X1[M x 128] @ W1(128x256, ld=256)  [+ X2 @ W2] [+ bias]
__global__ __launch_bounds__(256, 2) void node_pre(
    const float* __restrict__ X1, const float* __restrict__ W1,
    const float* __restrict__ X2, const float* __restrict__ W2,
    const float* __restrict__ bias, float* __restrict__ C, int M)
{
  __shared__ float xs[32][128];
  int row0 = blockIdx.x * 32;
  int c = threadIdx.x;  // 0..255 = output column
  float acc[32];
#pragma unroll
  for (int r = 0; r < 32; r++) acc[r] = 0.f;

  for (int pass = 0; pass < 2; ++pass) {
    const float* X = pass ? X2 : X1;
    const float* W = pass ? W2 : W1;
    if (X == nullptr) break;
    __syncthreads();
    // load 32x128 tile as float4s: 1024 float4, 4 per thread
    for (int i = threadIdx.x; i < 32 * 32; i += 256) {
      int r = i >> 5, q = i & 31;
      int row = row0 + r;
      float4 v = make_float4(0.f, 0.f, 0.f, 0.f);
      if (row < M) v = ((const float4*)(X + (size_t)row * 128))[q];
      ((float4*)&xs[r][0])[q] = v;
    }
    __syncthreads();
    for (int k = 0; k < 128; k += 4) {
      float w0 = W[(size_t)(k + 0) * 256 + c];
      float w1 = W[(size_t)(k + 1) * 256 + c];
      float w2 = W[(size_t)(k + 2) * 256 + c];
      float w3 = W[(size_t)(k + 3) * 256 + c];
#pragma unroll
      for (int r = 0; r < 32; r++) {
        float4 x = *(const float4*)&xs[r][k];
        acc[r] = fmaf(x.x, w0, fmaf(x.y, w1, fmaf(x.z, w2, fmaf(x.w, w3, acc[r]))));
      }
    }
  }
  float bv = bias ? bias[c] : 0.f;
  for (int r = 0; r < 32; r++) {
    int row = row0 + r;
    if (row < M) C[(size_t)row * 256 + c] = acc[r] + bv;
  }
}

// Per-edge kernel: 64 edges per 256-thread block.
__global__ __launch_bounds__(256, 2) void edge_kernel(
    const float* __restrict__ A, const float* __restrict__ B,
    const float* __restrict__ w1c, const float* __restrict__ Wm2,
    const float* __restrict__ bm2, const float* __restrict__ Wc1,
    const float* __restrict__ bc1, const float* __restrict__ Wc2,
    const float* __restrict__ bc2,
    const float* __restrict__ pos_src, const float* __restrict__ pos_tgt,
    const int* __restrict__ esrc, const int* __restrict__ etgt,
    float* __restrict__ agg, float* __restrict__ vel, int E)
{
  __shared__ int ss[64], ts[64];
  __shared__ float rels[64][4];
  __shared__ float hid[64 * 256];  // 64KB; later aliased: msg [0,8192), c1 [8192, 8192+64*65)
  int tid = threadIdx.x;
  int e0 = blockIdx.x * 64;

  if (tid < 64) {
    int e = e0 + tid;
    int s = 0, t = 0;
    if (e < E) { s = esrc[e]; t = etgt[e]; }
    ss[tid] = s; ts[tid] = t;
    float rx = pos_tgt[(size_t)t * 3 + 0] - pos_src[(size_t)s * 3 + 0];
    float ry = pos_tgt[(size_t)t * 3 + 1] - pos_src[(size_t)s * 3 + 1];
    float rz = pos_tgt[(size_t)t * 3 + 2] - pos_src[(size_t)s * 3 + 2];
    rels[tid][0] = rx; rels[tid][1] = ry; rels[tid][2] = rz;
    rels[tid][3] = rx * rx + ry * ry + rz * rz;
  }
  __syncthreads();

  // phase 1: hidden[r][c] = silu(A[s] + B[t] + sq * w1c), c = 0..255
  {
    int c = tid;
    float wv = w1c[c];
#pragma unroll 4
    for (int r = 0; r < 64; r++) {
      float pre = A[(size_t)ss[r] * 256 + c] + B[(size_t)ts[r] * 256 + c] + rels[r][3] * wv;
      hid[r * 256 + c] = silu_f(pre);
    }
  }
  __syncthreads();

  // phase 2: msg(64x128) = silu(hidden(64x256) @ Wm2(256x128) + bm2)
  int eg = tid >> 5;   // 0..7 -> rows eg*8..+7
  int cg = tid & 31;   // 0..31 -> cols cg*4..+3
  int j0 = cg * 4;
  float acc[8][4];
  {
    float b0 = bm2[j0], b1 = bm2[j0 + 1], b2 = bm2[j0 + 2], b3 = bm2[j0 + 3];
#pragma unroll
    for (int r = 0; r < 8; r++) { acc[r][0] = b0; acc[r][1] = b1; acc[r][2] = b2; acc[r][3] = b3; }
  }
  for (int k = 0; k < 256; k += 4) {
    float4 w0 = *(const float4*)&Wm2[(size_t)(k + 0) * 128 + j0];
    float4 w1 = *(const float4*)&Wm2[(size_t)(k + 1) * 128 + j0];
    float4 w2 = *(const float4*)&Wm2[(size_t)(k + 2) * 128 + j0];
    float4 w3 = *(const float4*)&Wm2[(size_t)(k + 3) * 128 + j0];
#pragma unroll
    for (int r = 0; r < 8; r++) {
      float4 h = *(const float4*)&hid[(eg * 8 + r) * 256 + k];
      acc[r][0] = fmaf(h.x, w0.x, fmaf(h.y, w1.x, fmaf(h.z, w2.x, fmaf(h.w, w3.x, acc[r][0]))));
      acc[r][1] = fmaf(h.x, w0.y, fmaf(h.y, w1.y, fmaf(h.z, w2.y, fmaf(h.w, w3.y, acc[r][1]))));
      acc[r][2] = fmaf(h.x, w0.z, fmaf(h.y, w1.z, fmaf(h.z, w2.z, fmaf(h.w, w3.z, acc[r][2]))));
      acc[r][3] = fmaf(h.x, w0.w, fmaf(h.y, w1.w, fmaf(h.z, w2.w, fmaf(h.w, w3.w, acc[r][3]))));
    }
  }
#pragma unroll
  for (int r = 0; r < 8; r++) {
    acc[r][0] = silu_f(acc[r][0]); acc[r][1] = silu_f(acc[r][1]);
    acc[r][2] = silu_f(acc[r][2]); acc[r][3] = silu_f(acc[r][3]);
  }
  __syncthreads();  // everyone done reading hidden
  float* msgs = hid;  // reuse [0, 8192)
#pragma unroll
  for (int r = 0; r < 8; r++) {
    int row = eg * 8 + r;
    *(float4*)&msgs[row * 128 + j0] = make_float4(acc[r][0], acc[r][1], acc[r][2], acc[r][3]);
    if (e0 + row < E) {
      float* dst = &agg[(size_t)ts[row] * 128 + j0];
      atomicAdd(dst + 0, acc[r][0]);
      atomicAdd(dst + 1, acc[r][1]);
      atomicAdd(dst + 2, acc[r][2]);
      atomicAdd(dst + 3, acc[r][3]);
    }
  }
  __syncthreads();

  // phase 3: C1(64x64) = silu(msg(64x128) @ Wc1(128x64) + bc1)
  float* c1s = hid + 8192;  // 64 rows * stride 65
  {
    int j = cg * 2;  // 0..62
    float a0[8], a1[8];
    float b0 = bc1[j], b1 = bc1[j + 1];
#pragma unroll
    for (int r = 0; r < 8; r++) { a0[r] = b0; a1[r] = b1; }
    for (int k = 0; k < 128; k += 4) {
      float2 wA = *(const float2*)&Wc1[(size_t)(k + 0) * 64 + j];
      float2 wB = *(const float2*)&Wc1[(size_t)(k + 1) * 64 + j];
      float2 wC = *(const float2*)&Wc1[(size_t)(k + 2) * 64 + j];
      float2 wD = *(const float2*)&Wc1[(size_t)(k + 3) * 64 + j];
#pragma unroll
      for (int r = 0; r < 8; r++) {
        float4 m = *(const float4*)&msgs[(eg * 8 + r) * 128 + k];
        a0[r] = fmaf(m.x, wA.x, fmaf(m.y, wB.x, fmaf(m.z, wC.x, fmaf(m.w, wD.x, a0[r]))));
        a1[r] = fmaf(m.x, wA.y, fmaf(m.y, wB.y, fmaf(m.z, wC.y, fmaf(m.w, wD.y, a1[r]))));
      }
    }
#pragma unroll
    for (int r = 0; r < 8; r++) {
      int row = eg * 8 + r;
      c1s[row * 65 + j] = silu_f(a0[r]);
      c1s[row * 65 + j + 1] = silu_f(a1[r]);
    }
  }
  __syncthreads();

  // phase 4: w = tanh(C1 @ Wc2 + bc2); vel[t] += w * rel
  if (tid < 64) {
    int row = tid;
    if (e0 + row < E) {
      float dotv = bc2[0];
#pragma unroll 8
      for (int k = 0; k < 64; k++) dotv = fmaf(c1s[row * 65 + k], Wc2[k], dotv);
      float w = tanhf(dotv);
      int t = ts[row];
      float* vp = &vel[(size_t)t * 3];
      atomicAdd(vp + 0, w * rels[row][0]);
      atomicAdd(vp + 1, w * rels[row][1]);
      atomicAdd(vp + 2, w * rels[row][2]);
    }
  }
}

// Per-target update MLP + layernorm. 32 targets per 256-thread block.
__global__ __launch_bounds__(256, 2) void tgt_update(
    const float* __restrict__ h_tgt, const float* __restrict__ agg,
    const float* __restrict__ Wu1, const float* __restrict__ bu1,
    const float* __restrict__ Wu2, const float* __restrict__ bu2,
    const float* __restrict__ gamma, const float* __restrict__ beta,
    float* __restrict__ out, int M)
{
  __shared__ float ht[32][132];
  __shared__ float xs[32][132];
  int row0 = blockIdx.x * 32;
  int tid = threadIdx.x;

  for (int i = tid; i < 32 * 32; i += 256) {
    int r = i >> 5, q = i & 31;
    int row = row0 + r;
    float4 a = make_float4(0.f, 0.f, 0.f, 0.f), g = a;
    if (row < M) {
      a = ((const float4*)(h_tgt + (size_t)row * 128))[q];
      g = ((const float4*)(agg + (size_t)row * 128))[q];
    }
    ((float4*)&ht[r][0])[q] = a;
    ((float4*)&xs[r][0])[q] = g;
  }
  __syncthreads();

  int j = tid & 127;
  int rg = tid >> 7;  // 0..1 -> rows rg*16..+15
  float acc[16];
  {
    float b = bu1[j];
#pragma unroll
    for (int r = 0; r < 16; r++) acc[r] = b;
  }
  for (int k = 0; k < 128; k += 4) {
    float w0 = Wu1[(size_t)(k + 0) * 128 + j];
    float w1 = Wu1[(size_t)(k + 1) * 128 + j];
    float w2 = Wu1[(size_t)(k + 2) * 128 + j];
    float w3 = Wu1[(size_t)(k + 3) * 128 + j];
#pragma unroll
    for (int r = 0; r < 16; r++) {
      float4 x = *(const float4*)&ht[rg * 16 + r][k];
      acc[r] = fmaf(x.x, w0, fmaf(x.y, w1, fmaf(x.z, w2, fmaf(x.w, w3, acc[r]))));
    }
  }
  for (int k = 0; k < 128; k += 4) {
    float w0 = Wu1[(size_t)(128 + k + 0) * 128 + j];
    float w1 = Wu1[(size_t)(128 + k + 1) * 128 + j];
    float w2 = Wu1[(size_t)(128 + k + 2) * 128 + j];
    float w3 = Wu1[(size_t)(128 + k + 3) * 128 + j];
#pragma unroll
    for (int r = 0; r < 16; r++) {
      float4 x = *(const float4*)&xs[rg * 16 + r][k];
      acc[r] = fmaf(x.x, w0, fmaf(x.y, w1, fmaf(x.z, w2, fmaf(x.w, w3, acc[r]))));
    }
  }
#pragma unroll
  for (int r = 0; r < 16; r++) acc[r] = silu_f(acc[r]);
  __syncthreads();
#pragma unroll
  for (int r = 0; r < 16; r++) xs[rg * 16 + r][j] = acc[r];
  __syncthreads();

  float acc2[16];
  {
    float b = bu2[j];
#pragma unroll
    for (int r = 0; r < 16; r++) acc2[r] = b;
  }
  for (int k = 0; k < 128; k += 4) {
    float w0 = Wu2[(size_t)(k + 0) * 128 + j];
    float w1 = Wu2[(size_t)(k + 1) * 128 + j];
    float w2 = Wu2[(size_t)(k + 2) * 128 + j];
    float w3 = Wu2[(size_t)(k + 3) * 128 + j];
#pragma unroll
    for (int r = 0; r < 16; r++) {
      float4 x = *(const float4*)&xs[rg * 16 + r][k];
      acc2[r] = fmaf(x.x, w0, fmaf(x.y, w1, fmaf(x.z, w2, fmaf(x.w, w3, acc2[r]))));
    }
  }
  __syncthreads();
#pragma unroll
  for (int r = 0; r < 16; r++) xs[rg * 16 + r][j] = acc2[r] + ht[rg * 16 + r][j];
  __syncthreads();

  // layernorm: 8 threads per row
  int row = tid >> 3, sub = tid & 7;
  float s = 0.f, s2 = 0.f;
#pragma unroll
  for (int q = 0; q < 16; q++) {
    float v = xs[row][sub * 16 + q];
    s += v; s2 += v * v;
  }
  for (int off = 1; off < 8; off <<= 1) {
    s += __shfl_xor(s, off, 64);
    s2 += __shfl_xor(s2, off, 64);
  }
  float mu = s * (1.f / 128.f);
  float var = s2 * (1.f / 128.f) - mu * mu;
  float rs = rsqrtf(var + 1e-5f);
  int orow = row0 + row;
  if (orow < M) {
#pragma unroll
    for (int q = 0; q < 16; q++) {
      int c = sub * 16 + q;
      out[(size_t)orow * 128 + c] = (xs[row][c] - mu) * rs * gamma[c] + beta[c];
    }
  }
}

extern "C" void kernel_launch(void* const* d_in, const int* in_sizes, int n_in,
                              void* d_out, int out_size, void* d_ws, size_t ws_size,
                              hipStream_t stream) {
  const float* h_src  = (const float*)d_in[0];
  const float* h_tgt  = (const float*)d_in[1];
  const float* pos_src = (const float*)d_in[2];
  const float* pos_tgt = (const float*)d_in[3];
  const float* t_emb  = (const float*)d_in[4];
  const float* W_m1 = (const float*)d_in[5];
  const float* b_m1 = (const float*)d_in[6];
  const float* W_m2 = (const float*)d_in[7];
  const float* b_m2 = (const float*)d_in[8];
  const float* W_c1 = (const float*)d_in[9];
  const float* b_c1 = (const float*)d_in[10];
  const float* W_c2 = (const float*)d_in[11];
  const float* b_c2 = (const float*)d_in[12];
  const float* W_u1 = (const float*)d_in[13];
  const float* b_u1 = (const float*)d_in[14];
  const float* W_u2 = (const float*)d_in[15];
  const float* b_u2 = (const float*)d_in[16];
  const float* gamma = (const float*)d_in[17];
  const float* beta  = (const float*)d_in[18];
  const int* esrc = (const int*)d_in[19];
  const int* etgt = (const int*)d_in[20];

  int n_src = in_sizes[0] / 128;
  int n_tgt = in_sizes[1] / 128;
  int E = in_sizes[19];

  float* ws = (float*)d_ws;
  float* A = ws;                                  // n_src x 256
  float* B = A + (size_t)n_src * 256;             // n_tgt x 256
  float* agg = B + (size_t)n_tgt * 256;           // n_tgt x 128
  float* out_h = (float*)d_out;                   // n_tgt x 128
  float* vel = out_h + (size_t)n_tgt * 128;       // n_tgt x 3

  hipMemsetAsync(agg, 0, (size_t)n_tgt * 128 * sizeof(float), stream);
  hipMemsetAsync(vel, 0, (size_t)n_tgt * 3 * sizeof(float), stream);

  dim3 blk(256);
  node_pre<<<(n_src + 31) / 32, blk, 0, stream>>>(
      h_src, W_m1, nullptr, nullptr, nullptr, A, n_src);
  node_pre<<<(n_tgt + 31) / 32, blk, 0, stream>>>(
      h_tgt, W_m1 + 128 * 256, t_emb, W_m1 + 257 * 256, b_m1, B, n_tgt);
  edge_kernel<<<(E + 63) / 64, blk, 0, stream>>>(
      A, B, W_m1 + 256 * 256, W_m2, b_m2, W_c1, b_c1, W_c2, b_c2,
      pos_src, pos_tgt, esrc, etgt, agg, vel, E);
  tgt_update<<<(n_tgt + 31) / 32, blk, 0, stream>>>(
      h_tgt, agg, W_u1, b_u1, W_u2, b_u2, gamma, beta, out_h, n_tgt);
}

// Round 3
// 1143.906 us; speedup vs baseline: 2.0137x; 2.0137x over previous
//
#include <hip/hip_runtime.h>

typedef __attribute__((ext_vector_type(8))) short bf16x8;
typedef __attribute__((ext_vector_type(4))) float f32x4;

__device__ __forceinline__ float silu_f(float x) {
  return x / (1.0f + __expf(-x));
}

__device__ __forceinline__ unsigned short f2bf(float f) {
  union { float f; unsigned int u; } x; x.f = f;
  unsigned int u = x.u + 0x7fffu + ((x.u >> 16) & 1u);  // RNE
  return (unsigned short)(u >> 16);
}

__device__ __forceinline__ float bf2f_lo(unsigned int packed) {
  return __uint_as_float(packed << 16);
}
__device__ __forceinline__ float bf2f_hi(unsigned int packed) {
  return __uint_as_float(packed & 0xffff0000u);
}

// Transpose+convert weights: Wm2(256x128 f32) -> Wm2T(128x256 bf16);
// Wc1(128x64 f32) -> Wc1T(64x128 bf16).
__global__ void prep_weights(const float* __restrict__ Wm2, const float* __restrict__ Wc1,
                             unsigned short* __restrict__ Wm2T, unsigned short* __restrict__ Wc1T)
{
  int i = blockIdx.x * 256 + threadIdx.x;
  if (i < 128 * 256) {
    int n = i >> 8, k = i & 255;
    Wm2T[i] = f2bf(Wm2[k * 128 + n]);
  }
  if (i < 64 * 128) {
    int n = i >> 7, k = i & 127;
    Wc1T[i] = f2bf(Wc1[k * 64 + n]);
  }
}

// C[M x 256] (bf16) = X1[M x 128] @ W1(128x256, ld=256) [+ X2 @ W2] [+ bias]
__global__ __launch_bounds__(256, 2) void node_pre(
    const float* __restrict__ X1, const float* __restrict__ W1,
    const float* __restrict__ X2, const float* __restrict__ W2,
    const float* __restrict__ bias, unsigned short* __restrict__ C, int M)
{
  __shared__ float xs[32][128];
  int row0 = blockIdx.x * 32;
  int c = threadIdx.x;
  float acc[32];
#pragma unroll
  for (int r = 0; r < 32; r++) acc[r] = 0.f;

  for (int pass = 0; pass < 2; ++pass) {
    const float* X = pass ? X2 : X1;
    const float* W = pass ? W2 : W1;
    if (X == nullptr) break;
    __syncthreads();
    for (int i = threadIdx.x; i < 32 * 32; i += 256) {
      int r = i >> 5, q = i & 31;
      int row = row0 + r;
      float4 v = make_float4(0.f, 0.f, 0.f, 0.f);
      if (row < M) v = ((const float4*)(X + (size_t)row * 128))[q];
      ((float4*)&xs[r][0])[q] = v;
    }
    __syncthreads();
    for (int k = 0; k < 128; k += 4) {
      float w0 = W[(size_t)(k + 0) * 256 + c];
      float w1 = W[(size_t)(k + 1) * 256 + c];
      float w2 = W[(size_t)(k + 2) * 256 + c];
      float w3 = W[(size_t)(k + 3) * 256 + c];
#pragma unroll
      for (int r = 0; r < 32; r++) {
        float4 x = *(const float4*)&xs[r][k];
        acc[r] = fmaf(x.x, w0, fmaf(x.y, w1, fmaf(x.z, w2, fmaf(x.w, w3, acc[r]))));
      }
    }
  }
  float bv = bias ? bias[c] : 0.f;
  for (int r = 0; r < 32; r++) {
    int row = row0 + r;
    if (row < M) C[(size_t)row * 256 + c] = f2bf(acc[r] + bv);
  }
}

// Per-edge MFMA kernel: 64 edges per 256-thread block (4 waves x 16 edges).
#define HID_LD 264   // 256 + 8 bf16 pad (row stride 528B, 16B-aligned)
#define MSG_LD 136   // 128 + 8 bf16 pad (row stride 272B)
__global__ __launch_bounds__(256, 3) void edge_mfma(
    const unsigned short* __restrict__ A, const unsigned short* __restrict__ B,
    const float* __restrict__ w1c,
    const unsigned short* __restrict__ Wm2T, const float* __restrict__ bm2,
    const unsigned short* __restrict__ Wc1T, const float* __restrict__ bc1,
    const float* __restrict__ Wc2, const float* __restrict__ bc2,
    const float* __restrict__ pos_src, const float* __restrict__ pos_tgt,
    const int* __restrict__ esrc, const int* __restrict__ etgt,
    float* __restrict__ agg, float* __restrict__ vel, int E)
{
  __shared__ int ss[64], ts[64];
  __shared__ float rels[64][4];
  __shared__ unsigned short hid[64 * HID_LD];   // 33792 B; aliased by c1 (f32, ld 68) later
  __shared__ unsigned short msgs[64 * MSG_LD];  // 17408 B

  int tid = threadIdx.x;
  int e0 = blockIdx.x * 64;

  if (tid < 64) {
    int e = e0 + tid;
    int s = 0, t = 0;
    if (e < E) { s = esrc[e]; t = etgt[e]; }
    ss[tid] = s; ts[tid] = t;
    float rx = pos_tgt[(size_t)t * 3 + 0] - pos_src[(size_t)s * 3 + 0];
    float ry = pos_tgt[(size_t)t * 3 + 1] - pos_src[(size_t)s * 3 + 1];
    float rz = pos_tgt[(size_t)t * 3 + 2] - pos_src[(size_t)s * 3 + 2];
    rels[tid][0] = rx; rels[tid][1] = ry; rels[tid][2] = rz;
    rels[tid][3] = rx * rx + ry * ry + rz * rz;
  }
  __syncthreads();

  // phase 1: hid[r][c] = bf16(silu(A[s][c] + B[t][c] + sq*w1c[c])), c=0..255
  {
    int c2 = tid & 127;            // column pair: cols 2*c2, 2*c2+1
    int r0 = (tid >> 7) * 32;      // rows 0..31 / 32..63
    float wv0 = w1c[2 * c2], wv1 = w1c[2 * c2 + 1];
#pragma unroll 4
    for (int rr = 0; rr < 32; rr++) {
      int r = r0 + rr;
      int s = ss[r], t = ts[r];
      unsigned int av = *(const unsigned int*)&A[(size_t)s * 256 + 2 * c2];
      unsigned int bv = *(const unsigned int*)&B[(size_t)t * 256 + 2 * c2];
      float sq = rels[r][3];
      float v0 = silu_f(bf2f_lo(av) + bf2f_lo(bv) + sq * wv0);
      float v1 = silu_f(bf2f_hi(av) + bf2f_hi(bv) + sq * wv1);
      unsigned int pk = ((unsigned int)f2bf(v1) << 16) | (unsigned int)f2bf(v0);
      *(unsigned int*)&hid[r * HID_LD + 2 * c2] = pk;
    }
  }
  __syncthreads();

  int w = tid >> 6, lane = tid & 63;
  int l15 = lane & 15, lg = lane >> 4;
  int R0 = w * 16;

  // phase 2: msg(64x128) = silu(hid(64x256) @ Wm2(256x128) + bm2), MFMA
  f32x4 acc[8];
#pragma unroll
  for (int f = 0; f < 8; f++) acc[f] = (f32x4){0.f, 0.f, 0.f, 0.f};
  {
    const unsigned short* hrow = &hid[(R0 + l15) * HID_LD];
#pragma unroll
    for (int ks = 0; ks < 8; ks++) {
      int kb = ks * 32 + lg * 8;
      bf16x8 a = *(const bf16x8*)&hrow[kb];
#pragma unroll
      for (int f = 0; f < 8; f++) {
        bf16x8 b = *(const bf16x8*)&Wm2T[(f * 16 + l15) * 256 + kb];
        acc[f] = __builtin_amdgcn_mfma_f32_16x16x32_bf16(a, b, acc[f], 0, 0, 0);
      }
    }
  }
#pragma unroll
  for (int f = 0; f < 8; f++) {
    int col = f * 16 + l15;
    float bias = bm2[col];
#pragma unroll
    for (int r = 0; r < 4; r++) {
      int row = R0 + lg * 4 + r;
      float v = silu_f(acc[f][r] + bias);
      msgs[row * MSG_LD + col] = f2bf(v);
      if (e0 + row < E)
        atomicAdd(&agg[(size_t)ts[row] * 128 + col], v);
    }
  }
  __syncthreads();

  // phase 3: c1(64x64) = silu(msg(64x128) @ Wc1(128x64) + bc1), MFMA
  f32x4 acc2[4];
#pragma unroll
  for (int f = 0; f < 4; f++) acc2[f] = (f32x4){0.f, 0.f, 0.f, 0.f};
  {
    const unsigned short* mrow = &msgs[(R0 + l15) * MSG_LD];
#pragma unroll
    for (int ks = 0; ks < 4; ks++) {
      int kb = ks * 32 + lg * 8;
      bf16x8 a = *(const bf16x8*)&mrow[kb];
#pragma unroll
      for (int f = 0; f < 4; f++) {
        bf16x8 b = *(const bf16x8*)&Wc1T[(f * 16 + l15) * 128 + kb];
        acc2[f] = __builtin_amdgcn_mfma_f32_16x16x32_bf16(a, b, acc2[f], 0, 0, 0);
      }
    }
  }
  float* c1 = (float*)hid;  // 64 rows, ld 68 floats (17408 B <= hid region)
#pragma unroll
  for (int f = 0; f < 4; f++) {
    int col = f * 16 + l15;
    float bias = bc1[col];
#pragma unroll
    for (int r = 0; r < 4; r++) {
      int row = R0 + lg * 4 + r;
      c1[row * 68 + col] = silu_f(acc2[f][r] + bias);
    }
  }
  __syncthreads();

  // phase 4: wgt = tanh(c1 @ Wc2 + bc2); vel[t] += wgt * rel
  {
    int row = tid >> 2, sub = tid & 3;
    const float* crow = &c1[row * 68 + sub * 16];
    float dot = 0.f;
#pragma unroll
    for (int k = 0; k < 16; k++) dot = fmaf(crow[k], Wc2[sub * 16 + k], dot);
    dot += __shfl_xor(dot, 1);
    dot += __shfl_xor(dot, 2);
    if (sub == 0 && e0 + row < E) {
      float wv = tanhf(dot + bc2[0]);
      int t = ts[row];
      atomicAdd(&vel[(size_t)t * 3 + 0], wv * rels[row][0]);
      atomicAdd(&vel[(size_t)t * 3 + 1], wv * rels[row][1]);
      atomicAdd(&vel[(size_t)t * 3 + 2], wv * rels[row][2]);
    }
  }
}

// Per-target update MLP + layernorm. 32 targets per 256-thread block.
__global__ __launch_bounds__(256, 2) void tgt_update(
    const float* __restrict__ h_tgt, const float* __restrict__ agg,
    const float* __restrict__ Wu1, const float* __restrict__ bu1,
    const float* __restrict__ Wu2, const float* __restrict__ bu2,
    const float* __restrict__ gamma, const float* __restrict__ beta,
    float* __restrict__ out, int M)
{
  __shared__ float ht[32][132];
  __shared__ float xs[32][132];
  int row0 = blockIdx.x * 32;
  int tid = threadIdx.x;

  for (int i = tid; i < 32 * 32; i += 256) {
    int r = i >> 5, q = i & 31;
    int row = row0 + r;
    float4 a = make_float4(0.f, 0.f, 0.f, 0.f), g = a;
    if (row < M) {
      a = ((const float4*)(h_tgt + (size_t)row * 128))[q];
      g = ((const float4*)(agg + (size_t)row * 128))[q];
    }
    ((float4*)&ht[r][0])[q] = a;
    ((float4*)&xs[r][0])[q] = g;
  }
  __syncthreads();

  int j = tid & 127;
  int rg = tid >> 7;
  float acc[16];
  {
    float b = bu1[j];
#pragma unroll
    for (int r = 0; r < 16; r++) acc[r] = b;
  }
  for (int k = 0; k < 128; k += 4) {
    float w0 = Wu1[(size_t)(k + 0) * 128 + j];
    float w1 = Wu1[(size_t)(k + 1) * 128 + j];
    float w2 = Wu1[(size_t)(k + 2) * 128 + j];
    float w3 = Wu1[(size_t)(k + 3) * 128 + j];
#pragma unroll
    for (int r = 0; r < 16; r++) {
      float4 x = *(const float4*)&ht[rg * 16 + r][k];
      acc[r] = fmaf(x.x, w0, fmaf(x.y, w1, fmaf(x.z, w2, fmaf(x.w, w3, acc[r]))));
    }
  }
  for (int k = 0; k < 128; k += 4) {
    float w0 = Wu1[(size_t)(128 + k + 0) * 128 + j];
    float w1 = Wu1[(size_t)(128 + k + 1) * 128 + j];
    float w2 = Wu1[(size_t)(128 + k + 2) * 128 + j];
    float w3 = Wu1[(size_t)(128 + k + 3) * 128 + j];
#pragma unroll
    for (int r = 0; r < 16; r++) {
      float4 x = *(const float4*)&xs[rg * 16 + r][k];
      acc[r] = fmaf(x.x, w0, fmaf(x.y, w1, fmaf(x.z, w2, fmaf(x.w, w3, acc[r]))));
    }
  }
#pragma unroll
  for (int r = 0; r < 16; r++) acc[r] = silu_f(acc[r]);
  __syncthreads();
#pragma unroll
  for (int r = 0; r < 16; r++) xs[rg * 16 + r][j] = acc[r];
  __syncthreads();

  float acc2[16];
  {
    float b = bu2[j];
#pragma unroll
    for (int r = 0; r < 16; r++) acc2[r] = b;
  }
  for (int k = 0; k < 128; k += 4) {
    float w0 = Wu2[(size_t)(k + 0) * 128 + j];
    float w1 = Wu2[(size_t)(k + 1) * 128 + j];
    float w2 = Wu2[(size_t)(k + 2) * 128 + j];
    float w3 = Wu2[(size_t)(k + 3) * 128 + j];
#pragma unroll
    for (int r = 0; r < 16; r++) {
      float4 x = *(const float4*)&xs[rg * 16 + r][k];
      acc2[r] = fmaf(x.x, w0, fmaf(x.y, w1, fmaf(x.z, w2, fmaf(x.w, w3, acc2[r]))));
    }
  }
  __syncthreads();
#pragma unroll
  for (int r = 0; r < 16; r++) xs[rg * 16 + r][j] = acc2[r] + ht[rg * 16 + r][j];
  __syncthreads();

  int row = tid >> 3, sub = tid & 7;
  float s = 0.f, s2 = 0.f;
#pragma unroll
  for (int q = 0; q < 16; q++) {
    float v = xs[row][sub * 16 + q];
    s += v; s2 += v * v;
  }
  for (int off = 1; off < 8; off <<= 1) {
    s += __shfl_xor(s, off, 64);
    s2 += __shfl_xor(s2, off, 64);
  }
  float mu = s * (1.f / 128.f);
  float var = s2 * (1.f / 128.f) - mu * mu;
  float rs = rsqrtf(var + 1e-5f);
  int orow = row0 + row;
  if (orow < M) {
#pragma unroll
    for (int q = 0; q < 16; q++) {
      int c = sub * 16 + q;
      out[(size_t)orow * 128 + c] = (xs[row][c] - mu) * rs * gamma[c] + beta[c];
    }
  }
}

extern "C" void kernel_launch(void* const* d_in, const int* in_sizes, int n_in,
                              void* d_out, int out_size, void* d_ws, size_t ws_size,
                              hipStream_t stream) {
  const float* h_src  = (const float*)d_in[0];
  const float* h_tgt  = (const float*)d_in[1];
  const float* pos_src = (const float*)d_in[2];
  const float* pos_tgt = (const float*)d_in[3];
  const float* t_emb  = (const float*)d_in[4];
  const float* W_m1 = (const float*)d_in[5];
  const float* b_m1 = (const float*)d_in[6];
  const float* W_m2 = (const float*)d_in[7];
  const float* b_m2 = (const float*)d_in[8];
  const float* W_c1 = (const float*)d_in[9];
  const float* b_c1 = (const float*)d_in[10];
  const float* W_c2 = (const float*)d_in[11];
  const float* b_c2 = (const float*)d_in[12];
  const float* W_u1 = (const float*)d_in[13];
  const float* b_u1 = (const float*)d_in[14];
  const float* W_u2 = (const float*)d_in[15];
  const float* b_u2 = (const float*)d_in[16];
  const float* gamma = (const float*)d_in[17];
  const float* beta  = (const float*)d_in[18];
  const int* esrc = (const int*)d_in[19];
  const int* etgt = (const int*)d_in[20];

  int n_src = in_sizes[0] / 128;
  int n_tgt = in_sizes[1] / 128;
  int E = in_sizes[19];

  // workspace layout (bytes)
  unsigned short* A    = (unsigned short*)d_ws;                 // n_src*256 bf16
  unsigned short* B    = A + (size_t)n_src * 256;               // n_tgt*256 bf16
  unsigned short* Wm2T = B + (size_t)n_tgt * 256;               // 128*256 bf16
  unsigned short* Wc1T = Wm2T + 128 * 256;                      // 64*128 bf16
  float* agg = (float*)(Wc1T + 64 * 128);                       // n_tgt*128 f32
  float* out_h = (float*)d_out;                                 // n_tgt x 128
  float* vel = out_h + (size_t)n_tgt * 128;                     // n_tgt x 3

  hipMemsetAsync(agg, 0, (size_t)n_tgt * 128 * sizeof(float), stream);
  hipMemsetAsync(vel, 0, (size_t)n_tgt * 3 * sizeof(float), stream);

  dim3 blk(256);
  prep_weights<<<128, blk, 0, stream>>>(W_m2, W_c1, Wm2T, Wc1T);
  node_pre<<<(n_src + 31) / 32, blk, 0, stream>>>(
      h_src, W_m1, nullptr, nullptr, nullptr, A, n_src);
  node_pre<<<(n_tgt + 31) / 32, blk, 0, stream>>>(
      h_tgt, W_m1 + 128 * 256, t_emb, W_m1 + 257 * 256, b_m1, B, n_tgt);
  edge_mfma<<<(E + 63) / 64, blk, 0, stream>>>(
      A, B, W_m1 + 256 * 256, Wm2T, b_m2, Wc1T, b_c1, W_c2, b_c2,
      pos_src, pos_tgt, esrc, etgt, agg, vel, E);
  tgt_update<<<(n_tgt + 31) / 32, blk, 0, stream>>>(
      h_tgt, agg, W_u1, b_u1, W_u2, b_u2, gamma, beta, out_h, n_tgt);
}